// Round 2
// baseline (711.104 us; speedup 1.0000x reference)
//
#include <hip/hip_runtime.h>
#include <math.h>

#define BB 64
#define TT 2048
#define DD 768
#define PP 1024
#define KK 8
#define TSPLIT 32
#define TCHUNK (TT / TSPLIT)   // 64
#define D4 (DD / 4)            // 192

// ---------------------------------------------------------------------------
// ws layout (4-byte units):
//   pmax   : float[BB*TSPLIT*DD] = 1572864  (6 MB, per-chunk token-max partials)
//   counts : int  [PP]           = 1024     (zeroed by k_maxpart block (0,0))
//   sim    : float[BB*PP]        = 65536
// xproj / major live only in LDS now — no global round-trips.
// ---------------------------------------------------------------------------

__device__ __forceinline__ float wave_sum(float v) {
    for (int off = 32; off > 0; off >>= 1) v += __shfl_down(v, off, 64);
    return v;
}

// order-preserving float->uint map (monotone for all non-NaN floats)
__device__ __forceinline__ unsigned int fmap(float f) {
    unsigned int b = __float_as_uint(f);
    return (b & 0x80000000u) ? ~b : (b | 0x80000000u);
}

// K1: single-pass token-max partials (non-atomic) + zero counts.
// grid (TSPLIT, BB), block 192.  Reads 402 MB — the one HBM-bound pass.
__global__ __launch_bounds__(192) void k_maxpart(const float* __restrict__ x,
                                                 float* __restrict__ pmax,
                                                 int* __restrict__ counts) {
    const int chunk = blockIdx.x, b = blockIdx.y, d4 = threadIdx.x;
    if (chunk == 0 && b == 0)
        for (int i = threadIdx.x; i < PP; i += 192) counts[i] = 0;
    const float4* x4 = (const float4*)x;
    size_t base = ((size_t)b * TT + (size_t)chunk * TCHUNK) * D4 + d4;
    float4 m = make_float4(-INFINITY, -INFINITY, -INFINITY, -INFINITY);
    #pragma unroll 8
    for (int t = 0; t < TCHUNK; ++t) {
        float4 v = x4[base + (size_t)t * D4];
        m.x = fmaxf(m.x, v.x); m.y = fmaxf(m.y, v.y);
        m.z = fmaxf(m.z, v.z); m.w = fmaxf(m.w, v.w);
    }
    float4* dst = (float4*)pmax + ((size_t)b * TSPLIT + chunk) * D4 + d4;
    *dst = m;  // coalesced, non-atomic; L2-resident (6 MB total)
}

// K2 (fused mid): per batch row b —
//   A: reduce 32 pmax partials -> xm (LDS)
//   B: xproj = xm @ W^T -> xp (LDS only) + ||xproj||^2
//   C: sim[b,:] = (xp/||xp||) . (prompt[p]/||prompt[p]||), keys built in-register
//   D: top-8 of the row (ties -> lowest index) -> counts atomicAdd
// grid BB, block 512 (8 waves).
__global__ __launch_bounds__(512) void k_mid(const float* __restrict__ pmax,
                                             const float* __restrict__ W,
                                             const float* __restrict__ prompt,
                                             float* __restrict__ sim,
                                             int* __restrict__ counts) {
    __shared__ float xm[DD];
    __shared__ float xp[DD];
    __shared__ float wss[8];
    __shared__ unsigned long long keys[PP];
    __shared__ unsigned long long wmax[8];
    __shared__ int sel[KK];
    const int b = blockIdx.x;
    const int tid = threadIdx.x, wave = tid >> 6, lane = tid & 63;

    // --- A: token-max across chunk partials ---
    if (tid < D4) {
        const float4* p4 = (const float4*)pmax + (size_t)b * TSPLIT * D4 + tid;
        float4 m = p4[0];
        #pragma unroll
        for (int c = 1; c < TSPLIT; ++c) {
            float4 v = p4[(size_t)c * D4];
            m.x = fmaxf(m.x, v.x); m.y = fmaxf(m.y, v.y);
            m.z = fmaxf(m.z, v.z); m.w = fmaxf(m.w, v.w);
        }
        ((float4*)xm)[tid] = m;
    }
    __syncthreads();

    // --- B: xproj (768 wave-dots, 96 per wave) ---
    const float4* xm4 = (const float4*)xm;
    float sacc = 0.f;
    #pragma unroll 2
    for (int k = 0; k < 96; ++k) {
        const int o = 8 * k + wave;
        const float4* w4 = (const float4*)(W + (size_t)o * DD);
        float acc = 0.f;
        #pragma unroll
        for (int j = 0; j < 3; ++j) {
            float4 a = xm4[j * 64 + lane];
            float4 w = w4[j * 64 + lane];
            acc += a.x * w.x + a.y * w.y + a.z * w.z + a.w * w.w;
        }
        acc = wave_sum(acc);
        if (lane == 0) { xp[o] = acc; sacc += acc * acc; }
    }
    if (lane == 0) wss[wave] = sacc;
    __syncthreads();
    float ss = 0.f;
    #pragma unroll
    for (int w = 0; w < 8; ++w) ss += wss[w];
    const float xs = 1.0f / sqrtf(fmaxf(ss, 1e-12f));

    // --- C: sim row (1024 wave-dots, 128 per wave), pscale inline ---
    const float4* xp4 = (const float4*)xp;
    #pragma unroll 2
    for (int k = 0; k < 128; ++k) {
        const int p = 8 * k + wave;
        const float4* pr4 = (const float4*)(prompt + (size_t)p * DD);
        float acc = 0.f, ps = 0.f;
        #pragma unroll
        for (int j = 0; j < 3; ++j) {
            float4 a = xp4[j * 64 + lane];
            float4 v = pr4[j * 64 + lane];
            acc += a.x * v.x + a.y * v.y + a.z * v.z + a.w * v.w;
            ps  += v.x * v.x + v.y * v.y + v.z * v.z + v.w * v.w;
        }
        acc = wave_sum(acc);
        ps  = wave_sum(ps);
        if (lane == 0) {
            float s = acc * xs * (1.0f / sqrtf(fmaxf(ps, 1e-12f)));
            sim[b * PP + p] = s;
            keys[p] = ((unsigned long long)fmap(s) << 32)
                    | (unsigned int)(PP - 1 - p);
        }
    }
    __syncthreads();

    // --- D: top-8 of the row (ties -> lowest index) ---
    for (int it = 0; it < KK; ++it) {
        unsigned long long mk = 0;
        #pragma unroll
        for (int p = tid; p < PP; p += 512) {
            unsigned long long v = keys[p];
            if (v > mk) mk = v;
        }
        for (int off = 32; off > 0; off >>= 1) {
            unsigned long long o = __shfl_down(mk, off, 64);
            if (o > mk) mk = o;
        }
        if (lane == 0) wmax[wave] = mk;
        __syncthreads();
        if (tid == 0) {
            unsigned long long m = wmax[0];
            for (int w = 1; w < 8; ++w) if (wmax[w] > m) m = wmax[w];
            int p = PP - 1 - (int)(m & 0xFFFFFFFFu);
            sel[it] = p;
            keys[p] = 0ull;
        }
        __syncthreads();
    }
    if (tid < KK) atomicAdd(&counts[sel[tid]], 1);
}

// K3 (fused tail): every block computes the deterministic top-8 of counts
// in LDS (ties -> lowest id, ordered), then does its slice of the output.
// grid BB*KK + 1, block 256.
__global__ __launch_bounds__(256) void k_out(const float* __restrict__ prompt,
                                             const float* __restrict__ sim,
                                             const int* __restrict__ counts,
                                             float* __restrict__ out) {
    __shared__ unsigned long long keys[PP];
    __shared__ unsigned long long wmax[4];
    __shared__ int sel[KK];
    const int tid = threadIdx.x;
    const int lane = tid & 63, wave = tid >> 6;
    for (int p = tid; p < PP; p += 256)
        keys[p] = ((unsigned long long)(unsigned int)counts[p] << 32)
                | (unsigned int)(PP - 1 - p);
    __syncthreads();
    for (int it = 0; it < KK; ++it) {
        unsigned long long mk = 0;
        #pragma unroll
        for (int p = tid; p < PP; p += 256) {
            unsigned long long v = keys[p];
            if (v > mk) mk = v;
        }
        for (int off = 32; off > 0; off >>= 1) {
            unsigned long long o = __shfl_down(mk, off, 64);
            if (o > mk) mk = o;
        }
        if (lane == 0) wmax[wave] = mk;
        __syncthreads();
        if (tid == 0) {
            unsigned long long m = wmax[0];
            for (int w = 1; w < 4; ++w) if (wmax[w] > m) m = wmax[w];
            int p = PP - 1 - (int)(m & 0xFFFFFFFFu);
            sel[it] = p;
            keys[p] = 0ull;
        }
        __syncthreads();
    }

    if (blockIdx.x < BB * KK) {
        const int b = blockIdx.x >> 3, k = blockIdx.x & 7;
        const int id = sel[k];
        const float* src = prompt + (size_t)id * DD;
        float* dst = out + 1 + ((size_t)(b * KK + k)) * DD;
        for (int i = tid; i < DD; i += 256) dst[i] = src[i];
    } else {
        __shared__ float wsum[4];
        float s = 0.f;
        for (int i = tid; i < BB * KK; i += 256) {
            const int b = i >> 3, k = i & 7;
            s += sim[b * PP + sel[k]];
        }
        s = wave_sum(s);
        if (lane == 0) wsum[wave] = s;
        __syncthreads();
        if (tid == 0) out[0] = (wsum[0] + wsum[1] + wsum[2] + wsum[3]) / (float)BB;
    }
}

extern "C" void kernel_launch(void* const* d_in, const int* in_sizes, int n_in,
                              void* d_out, int out_size, void* d_ws, size_t ws_size,
                              hipStream_t stream) {
    const float* x      = (const float*)d_in[0];   // [64,2048,768]
    const float* prompt = (const float*)d_in[1];   // [1024,768]
    const float* W      = (const float*)d_in[2];   // [768,768]
    float* out = (float*)d_out;

    float* ws     = (float*)d_ws;
    float* pmax   = ws;                                        // BB*TSPLIT*DD
    int*   counts = (int*)(pmax + (size_t)BB * TSPLIT * DD);   // PP
    float* sim    = (float*)(counts + PP);                     // BB*PP

    k_maxpart<<<dim3(TSPLIT, BB), 192, 0, stream>>>(x, pmax, counts);
    k_mid<<<BB, 512, 0, stream>>>(pmax, W, prompt, sim, counts);
    k_out<<<BB * KK + 1, 256, 0, stream>>>(prompt, sim, counts, out);
}

// Round 3
// 608.277 us; speedup vs baseline: 1.1690x; 1.1690x over previous
//
#include <hip/hip_runtime.h>
#include <math.h>

#define BB 64
#define TT 2048
#define DD 768
#define PP 1024
#define KK 8
#define TSPLIT 32
#define TCHUNK (TT / TSPLIT)   // 64
#define D4 (DD / 4)            // 192

// ---------------------------------------------------------------------------
// ws layout (4-byte units):
//   pmax   : float[BB*TSPLIT*DD] = 1572864  (6 MB, per-chunk token-max partials)
//   counts : int  [PP]           = 1024     (zeroed by k_maxpart block (0,0))
//   sim    : float[BB*PP]        = 65536
//   xproj  : float[BB*DD]        = 49152
// major lives only in LDS (replicated counts-top-8 in k_out).
// ---------------------------------------------------------------------------

__device__ __forceinline__ float wave_sum(float v) {
    for (int off = 32; off > 0; off >>= 1) v += __shfl_down(v, off, 64);
    return v;
}

// order-preserving float->uint map (monotone for all non-NaN floats)
__device__ __forceinline__ unsigned int fmap(float f) {
    unsigned int b = __float_as_uint(f);
    return (b & 0x80000000u) ? ~b : (b | 0x80000000u);
}

// K1: single-pass token-max partials (non-atomic) + zero counts.
// grid (TSPLIT, BB), block 192.  Reads 402 MB — the one HBM-bound pass.
__global__ __launch_bounds__(192) void k_maxpart(const float* __restrict__ x,
                                                 float* __restrict__ pmax,
                                                 int* __restrict__ counts) {
    const int chunk = blockIdx.x, b = blockIdx.y, d4 = threadIdx.x;
    if (chunk == 0 && b == 0)
        for (int i = threadIdx.x; i < PP; i += 192) counts[i] = 0;
    const float4* x4 = (const float4*)x;
    size_t base = ((size_t)b * TT + (size_t)chunk * TCHUNK) * D4 + d4;
    float4 m = make_float4(-INFINITY, -INFINITY, -INFINITY, -INFINITY);
    #pragma unroll 8
    for (int t = 0; t < TCHUNK; ++t) {
        float4 v = x4[base + (size_t)t * D4];
        m.x = fmaxf(m.x, v.x); m.y = fmaxf(m.y, v.y);
        m.z = fmaxf(m.z, v.z); m.w = fmaxf(m.w, v.w);
    }
    float4* dst = (float4*)pmax + ((size_t)b * TSPLIT + chunk) * D4 + d4;
    *dst = m;  // coalesced, non-atomic; L2-resident (6 MB total)
}

// K2: reduce partial maxes -> xm (LDS), then x_proj = xm @ W^T.
// grid (4, BB) = 256 blocks, block 256 (4 waves, 48 outputs each).
__global__ __launch_bounds__(256) void k_proj(const float* __restrict__ pmax,
                                              const float* __restrict__ W,
                                              float* __restrict__ xproj) {
    __shared__ float xm[DD];
    const int b = blockIdx.y;
    const int o0 = blockIdx.x * 192;
    if (threadIdx.x < D4) {
        const float4* p4 = (const float4*)pmax + (size_t)b * TSPLIT * D4 + threadIdx.x;
        float4 m = p4[0];
        #pragma unroll
        for (int c = 1; c < TSPLIT; ++c) {
            float4 v = p4[(size_t)c * D4];
            m.x = fmaxf(m.x, v.x); m.y = fmaxf(m.y, v.y);
            m.z = fmaxf(m.z, v.z); m.w = fmaxf(m.w, v.w);
        }
        ((float4*)xm)[threadIdx.x] = m;
    }
    __syncthreads();
    const int wave = threadIdx.x >> 6, lane = threadIdx.x & 63;
    const float4* xm4 = (const float4*)xm;
    for (int k = 0; k < 48; ++k) {
        const int o = o0 + 4 * k + wave;
        const float4* w4 = (const float4*)(W + (size_t)o * DD);
        float acc = 0.f;
        #pragma unroll
        for (int j = 0; j < 3; ++j) {
            float4 a = xm4[j * 64 + lane];
            float4 w = w4[j * 64 + lane];
            acc += a.x * w.x + a.y * w.y + a.z * w.z + a.w * w.w;
        }
        acc = wave_sum(acc);
        if (lane == 0) xproj[b * DD + o] = acc;
    }
}

// K3: sim[b,p] = dot(xproj[b], prompt[p]) * rsqrt(||xproj||^2) * rsqrt(||prompt[p]||^2).
// xs from the LDS copy; pscale inline from the same prompt loads.
// grid (8, BB) = 512 blocks, block 256 (4 waves, 32 p's each).
__global__ __launch_bounds__(256) void k_sim(const float* __restrict__ xproj,
                                             const float* __restrict__ prompt,
                                             float* __restrict__ sim) {
    __shared__ float xp[DD];
    __shared__ float wss[4];
    const int b = blockIdx.y;
    const int p0 = blockIdx.x * 128;
    float ssl = 0.f;
    for (int i = threadIdx.x; i < DD; i += 256) {
        float v = xproj[b * DD + i];
        xp[i] = v;
        ssl += v * v;
    }
    ssl = wave_sum(ssl);
    const int wave = threadIdx.x >> 6, lane = threadIdx.x & 63;
    if (lane == 0) wss[wave] = ssl;
    __syncthreads();
    const float xs = 1.0f / sqrtf(fmaxf(wss[0] + wss[1] + wss[2] + wss[3], 1e-12f));
    const float4* xp4 = (const float4*)xp;
    for (int k = 0; k < 32; ++k) {
        const int p = p0 + 4 * k + wave;
        const float4* pr4 = (const float4*)(prompt + (size_t)p * DD);
        float acc = 0.f, ps = 0.f;
        #pragma unroll
        for (int j = 0; j < 3; ++j) {
            float4 a = xp4[j * 64 + lane];
            float4 v = pr4[j * 64 + lane];
            acc += a.x * v.x + a.y * v.y + a.z * v.z + a.w * v.w;
            ps  += v.x * v.x + v.y * v.y + v.z * v.z + v.w * v.w;
        }
        acc = wave_sum(acc);
        ps  = wave_sum(ps);
        if (lane == 0)
            sim[b * PP + p] = acc * xs * (1.0f / sqrtf(fmaxf(ps, 1e-12f)));
    }
}

// K4: per-row top-8 (ties -> lowest index), then bincount via atomics.
// grid BB, block 256.
__global__ __launch_bounds__(256) void k_topk_rows(const float* __restrict__ sim,
                                                   int* __restrict__ counts) {
    __shared__ unsigned long long keys[PP];
    __shared__ unsigned long long wmax[4];
    __shared__ int sel[KK];
    const int b = blockIdx.x, tid = threadIdx.x;
    const int lane = tid & 63, wave = tid >> 6;
    for (int p = tid; p < PP; p += 256) {
        unsigned long long k = ((unsigned long long)fmap(sim[b * PP + p]) << 32)
                             | (unsigned int)(PP - 1 - p);
        keys[p] = k;
    }
    __syncthreads();
    for (int it = 0; it < KK; ++it) {
        unsigned long long mk = 0;
        for (int p = tid; p < PP; p += 256) {
            unsigned long long v = keys[p];
            if (v > mk) mk = v;
        }
        for (int off = 32; off > 0; off >>= 1) {
            unsigned long long o = __shfl_down(mk, off, 64);
            if (o > mk) mk = o;
        }
        if (lane == 0) wmax[wave] = mk;
        __syncthreads();
        if (tid == 0) {
            unsigned long long m = wmax[0];
            for (int w = 1; w < 4; ++w) if (wmax[w] > m) m = wmax[w];
            int p = PP - 1 - (int)(m & 0xFFFFFFFFu);
            sel[it] = p;
            keys[p] = 0ull;
        }
        __syncthreads();
    }
    if (tid < KK) atomicAdd(&counts[sel[tid]], 1);
}

// K5 (fused tail): every block redundantly computes the deterministic top-8
// of counts in LDS (ties -> lowest id, ordered, ~2 µs fully parallel), then
// does its slice of the output.  Eliminates the grid-1 serial kernel.
// grid BB*KK + 1, block 256.
__global__ __launch_bounds__(256) void k_out(const float* __restrict__ prompt,
                                             const float* __restrict__ sim,
                                             const int* __restrict__ counts,
                                             float* __restrict__ out) {
    __shared__ unsigned long long keys[PP];
    __shared__ unsigned long long wmax[4];
    __shared__ int sel[KK];
    const int tid = threadIdx.x;
    const int lane = tid & 63, wave = tid >> 6;
    for (int p = tid; p < PP; p += 256)
        keys[p] = ((unsigned long long)(unsigned int)counts[p] << 32)
                | (unsigned int)(PP - 1 - p);
    __syncthreads();
    for (int it = 0; it < KK; ++it) {
        unsigned long long mk = 0;
        for (int p = tid; p < PP; p += 256) {
            unsigned long long v = keys[p];
            if (v > mk) mk = v;
        }
        for (int off = 32; off > 0; off >>= 1) {
            unsigned long long o = __shfl_down(mk, off, 64);
            if (o > mk) mk = o;
        }
        if (lane == 0) wmax[wave] = mk;
        __syncthreads();
        if (tid == 0) {
            unsigned long long m = wmax[0];
            for (int w = 1; w < 4; ++w) if (wmax[w] > m) m = wmax[w];
            int p = PP - 1 - (int)(m & 0xFFFFFFFFu);
            sel[it] = p;
            keys[p] = 0ull;
        }
        __syncthreads();
    }

    if (blockIdx.x < BB * KK) {
        const int b = blockIdx.x >> 3, k = blockIdx.x & 7;
        const int id = sel[k];
        const float* src = prompt + (size_t)id * DD;
        float* dst = out + 1 + ((size_t)(b * KK + k)) * DD;
        for (int i = tid; i < DD; i += 256) dst[i] = src[i];
    } else {
        __shared__ float wsum[4];
        float s = 0.f;
        for (int i = tid; i < BB * KK; i += 256) {
            const int b = i >> 3, k = i & 7;
            s += sim[b * PP + sel[k]];
        }
        s = wave_sum(s);
        if (lane == 0) wsum[wave] = s;
        __syncthreads();
        if (tid == 0) out[0] = (wsum[0] + wsum[1] + wsum[2] + wsum[3]) / (float)BB;
    }
}

extern "C" void kernel_launch(void* const* d_in, const int* in_sizes, int n_in,
                              void* d_out, int out_size, void* d_ws, size_t ws_size,
                              hipStream_t stream) {
    const float* x      = (const float*)d_in[0];   // [64,2048,768]
    const float* prompt = (const float*)d_in[1];   // [1024,768]
    const float* W      = (const float*)d_in[2];   // [768,768]
    float* out = (float*)d_out;

    float* ws     = (float*)d_ws;
    float* pmax   = ws;                                        // BB*TSPLIT*DD
    int*   counts = (int*)(pmax + (size_t)BB * TSPLIT * DD);   // PP
    float* sim    = (float*)(counts + PP);                     // BB*PP
    float* xproj  = sim + (size_t)BB * PP;                     // BB*DD

    k_maxpart<<<dim3(TSPLIT, BB), 192, 0, stream>>>(x, pmax, counts);
    k_proj<<<dim3(4, BB), 256, 0, stream>>>(pmax, W, xproj);
    k_sim<<<dim3(8, BB), 256, 0, stream>>>(xproj, prompt, sim);
    k_topk_rows<<<BB, 256, 0, stream>>>(sim, counts);
    k_out<<<BB * KK + 1, 256, 0, stream>>>(prompt, sim, counts, out);
}